// Round 2
// baseline (325.552 us; speedup 1.0000x reference)
//
#include <hip/hip_runtime.h>

#define NG 20000

// single-instruction rotate (v_alignbit_b32): rotl(x,r) == alignbit(x,x,32-r)
__device__ __forceinline__ unsigned rotl32(unsigned x, int r) {
  return __builtin_amdgcn_alignbit(x, x, 32 - r);
}

// ---------- JAX threefry2x32, key = (0, 42) ----------
__device__ __forceinline__ void threefry2x32(unsigned x0, unsigned x1,
                                             unsigned& o0, unsigned& o1) {
  const unsigned ks0 = 0u;
  const unsigned ks1 = 42u;
  const unsigned ks2 = 0x1BD11BDAu ^ 0u ^ 42u;
  x0 += ks0; x1 += ks1;
#define TFR(r) { x0 += x1; x1 = rotl32(x1, (r)); x1 ^= x0; }
  TFR(13) TFR(15) TFR(26) TFR(6)
  x0 += ks1; x1 += ks2 + 1u;
  TFR(17) TFR(29) TFR(16) TFR(24)
  x0 += ks2; x1 += ks0 + 2u;
  TFR(13) TFR(15) TFR(26) TFR(6)
  x0 += ks0; x1 += ks1 + 3u;
  TFR(17) TFR(29) TFR(16) TFR(24)
  x0 += ks1; x1 += ks2 + 4u;
  TFR(13) TFR(15) TFR(26) TFR(6)
  x0 += ks2; x1 += ks0 + 5u;
#undef TFR
  o0 = x0; o1 = x1;
}

// JAX threefry_partitionable: bits(i) = o0 ^ o1 of threefry((0,42),(0,i))
__device__ __forceinline__ unsigned tfbits(unsigned ctr) {
  unsigned o0, o1;
  threefry2x32(0u, ctr, o0, o1);
  return o0 ^ o1;
}

// fp32 fast-screen gumbel, constant-folded: g = -ln2*log2(-log2(u)) - ln(ln2)
__device__ __forceinline__ float gumbel32(unsigned bits) {
  float f = __uint_as_float((bits >> 9) | 0x3f800000u) - 1.0f;
  float u = fmaxf(f, 1.17549435e-38f);
  const float l2u = __log2f(u);                     // strictly < 0
  return fmaf(-0.69314718056f, __log2f(-l2u), 0.3665129206f);
}

// exact fp64 gumbel; u is a 23-bit dyadic rational, exact in double
__device__ __forceinline__ double gumbel64(unsigned bits) {
  float f = __uint_as_float((bits >> 9) | 0x3f800000u) - 1.0f;
  double u = (double)fmaxf(f, 1.17549435e-38f);
  return -log(-log(u));
}

// pack fp64 score (top 49 monotone bits) + 15-bit (32767-n): u64 max == (score, then smaller n)
__device__ __forceinline__ unsigned long long packcell(double v, int n) {
  unsigned long long u = (unsigned long long)__double_as_longlong(v);
  u = (u >> 63) ? ~u : (u | 0x8000000000000000ull);
  return (u & 0xFFFFFFFFFFFF8000ull) | (unsigned long long)(32767 - n);
}

// ---------- prep: Wf=Wk@W1k (fp64 math, fp32 store), Q, qbT; c12; zero cells ----------
__global__ __launch_bounds__(128) void kprep(
    const float* __restrict__ pe, const float* __restrict__ Wq,
    const float* __restrict__ bq, const float* __restrict__ Wk,
    const float* __restrict__ bk, const float* __restrict__ W1,
    const float* __restrict__ b1, const float* __restrict__ w2,
    float* __restrict__ Wf32, double* __restrict__ qbT,
    float* __restrict__ Qm, unsigned long long* __restrict__ cells,
    double2* __restrict__ c12) {
  __shared__ float L[512];
  __shared__ double Ld[128];
  const int t = threadIdx.x;
  const int bid = blockIdx.x;
  if (bid < 256) {
    L[t] = Wk[bid * 128 + t];
    __syncthreads();
    double acc = 0.0;
    #pragma unroll 16
    for (int j = 0; j < 128; ++j)
      acc = fma((double)L[j], (double)W1[(128 + j) * 128 + t], acc);
    Wf32[bid * 128 + t] = (float)acc;
  } else if (bid < 320) {
    const int b = bid - 256;
    #pragma unroll
    for (int i = 0; i < 4; ++i) L[t + 128 * i] = pe[b * 512 + t + 128 * i];
    __syncthreads();
    double q = (double)bq[t];
    #pragma unroll 16
    for (int f = 0; f < 512; ++f)
      q = fma((double)L[f], (double)Wq[f * 128 + t], q);
    Qm[b * 128 + t] = (float)q;   // epilogue path stays fp32
    Ld[t] = q;
    __syncthreads();
    // qb[b,d=t] = Q@W1[:128] + b1 + bk@W1[128:]; store transposed qbT[d][b]
    double acc = (double)b1[t];
    #pragma unroll 8
    for (int j = 0; j < 128; ++j) {
      acc = fma(Ld[j], (double)W1[j * 128 + t], acc);
      acc = fma((double)bk[j], (double)W1[(128 + j) * 128 + t], acc);
    }
    qbT[t * 64 + b] = acc;
  } else {
    for (int i = t; i < 1280; i += 128) cells[i] = 0ull;
    const double w2d = (double)w2[t];
    c12[t] = make_double2(0.55 * w2d, 0.45 * w2d);
  }
}

// ---------- fully fused: kp(fp32 GEMM) + sim(fp64) + screen + exact + atomic ----------
// block = 256 threads, 8 genes (2500 blocks). 12 KB LDS + launch_bounds(256,8)
// -> 8 blocks/CU resident (8 waves/SIMD) vs 4.9 before: occupancy is the lever,
// total per-phase work is invariant under the gene partition.
// Phase 1: wave wv owns genes wv*2..wv*2+1; thread owns d = 2*lane, 2*lane+1
//   (float2 W-stream: half the VMEM insts); ge tile in LDS (broadcast
//   ds_read_b128), Wf32 depth-2 register stream. fp32 fmaf, per-acc f
//   ascending -> kp bit-identical to the verified kernel.
// Phase 2: kp -> kpL; wave wv computes fp64 sim for genes {wv, wv+4},
//   lane = batch; stores (float)(2*sim) to simLf[b][g] ([64][9], 9 coprime 32
//   -> conflict-free).
// Phase 3: thread handles 5 cells (cell = i*256+t = b*20+k); per cell: fp32
//   top-2 screen over the block's 8 genes, fp64-exact winner (+ runner-up iff
//   gap < 1e-4), one fire-and-forget atomicMax per cell. Max-of-window-maxima
//   with exact window winners == global exact argmax (window-size-independent).
__global__ __launch_bounds__(256, 8) void kfused(
    const float* __restrict__ ge, const float* __restrict__ Wf32,
    const double* __restrict__ qbT, const double2* __restrict__ c12,
    unsigned long long* __restrict__ cells) {
  __shared__ float SB[2048];    // phase1: geL (8 KB); phase2/3: simLf [64][9]
  __shared__ float kpL[1024];   // kp[8][128]
  float* geL = SB;
  float* simLf = SB;
  const int t = threadIdx.x;
  const int wv = t >> 6;
  const int lane = t & 63;
  const int g0 = blockIdx.x * 8;     // 2500 blocks * 8 genes

  // stage ge tile (8 genes x 256 f) -> LDS: 2 independent float4 per thread
  {
    const float4* src = (const float4*)(ge + (size_t)g0 * 256);
    float4* dst = (float4*)geL;
    dst[t] = src[t];
    dst[t + 256] = src[t + 256];
  }
  __syncthreads();

  // ---- phase 1: fp32 GEMM from LDS genes + streamed Wf32 (float2 over d) ----
  float acc[2][2];
  acc[0][0] = acc[0][1] = acc[1][0] = acc[1][1] = 0.f;
  const float2* wb = (const float2*)Wf32 + lane;   // element f*64+lane = d {2l,2l+1}
  const float* gL = geL + (wv * 2) * 256;

  float2 wc[4];
  #pragma unroll
  for (int ff = 0; ff < 4; ++ff) wc[ff] = wb[ff * 64];
  for (int f0 = 0; f0 < 256; f0 += 4) {
    float2 wn[4];
    if (f0 < 252) {
      #pragma unroll
      for (int ff = 0; ff < 4; ++ff) wn[ff] = wb[(f0 + 4 + ff) * 64];
    }
    #pragma unroll
    for (int j = 0; j < 2; ++j) {
      const float4 gv = *(const float4*)(gL + j * 256 + f0);  // ds_read_b128 bcast
      acc[j][0] = fmaf(gv.x, wc[0].x, acc[j][0]);
      acc[j][1] = fmaf(gv.x, wc[0].y, acc[j][1]);
      acc[j][0] = fmaf(gv.y, wc[1].x, acc[j][0]);
      acc[j][1] = fmaf(gv.y, wc[1].y, acc[j][1]);
      acc[j][0] = fmaf(gv.z, wc[2].x, acc[j][0]);
      acc[j][1] = fmaf(gv.z, wc[2].y, acc[j][1]);
      acc[j][0] = fmaf(gv.w, wc[3].x, acc[j][0]);
      acc[j][1] = fmaf(gv.w, wc[3].y, acc[j][1]);
    }
    #pragma unroll
    for (int ff = 0; ff < 4; ++ff) wc[ff] = wn[ff];
  }

  __syncthreads();   // geL reads done (SB about to be reused as simLf)
  #pragma unroll
  for (int j = 0; j < 2; ++j)
    ((float2*)(kpL + (wv * 2 + j) * 128))[lane] =
        make_float2(acc[j][0], acc[j][1]);
  __syncthreads();

  // ---- phase 2: fp64 sim (2 genes/wave, lane = batch) ----
  double s[2];
  s[0] = 0.0; s[1] = 0.0;
  for (int dd = 0; dd < 128; ++dd) {
    const double2 cc = c12[dd];                   // uniform -> s_load
    const double qv = qbT[dd * 64 + lane];        // coalesced, L1-hot
    #pragma unroll
    for (int j = 0; j < 2; ++j) {
      const double kv = (double)kpL[(wv + j * 4) * 128 + dd];  // broadcast
      const double tt = qv + kv;
      s[j] = fma(tt, cc.x, s[j]);
      s[j] = fma(fabs(tt), cc.y, s[j]);
    }
  }
  #pragma unroll
  for (int j = 0; j < 2; ++j)
    simLf[lane * 9 + (wv + j * 4)] = (float)(2.0 * s[j]);
  __syncthreads();

  // ---- phase 3: per-cell screen over this block's 8 genes ----
  #pragma unroll
  for (int i = 0; i < 5; ++i) {
    const int cell = i * 256 + t;                 // = b*20 + k, 0..1279
    const int b = (unsigned)cell / 20u;
    const float* sb = simLf + b * 9;
    float m1 = -3e38f, m2 = -3e38f;
    int n1 = -1, n2 = -1;
    unsigned c1 = 0, c2 = 0;
    const unsigned ib = (unsigned)cell * 20000u + (unsigned)g0;
    #pragma unroll 4
    for (int g = 0; g < 8; ++g) {
      const unsigned bb = tfbits(ib + (unsigned)g);
      const float sc = sb[g] + gumbel32(bb);
      if (sc > m1) { m2 = m1; n2 = n1; c2 = c1; m1 = sc; n1 = g; c1 = bb; }
      else if (sc > m2) { m2 = sc; n2 = g; c2 = bb; }
    }
    unsigned long long pb =
        packcell((double)sb[n1] + gumbel64(c1), g0 + n1);
    if (n2 >= 0 && (m1 - m2) < 1e-4f) {           // screen err 2e-5 << margin
      const unsigned long long u2 =
          packcell((double)sb[n2] + gumbel64(c2), g0 + n2);
      if (u2 > pb) pb = u2;
    }
    atomicMax(&cells[cell], pb);
  }
}

// ---------- epilogue (fp32): 5 interleaved V-GEMVs per wave, softmax over K, context ----------
__global__ __launch_bounds__(256) void kfinal(
    const float* __restrict__ ge, const float* __restrict__ Wv,
    const float* __restrict__ bv, const float* __restrict__ Qm,
    const unsigned long long* __restrict__ cells, float* __restrict__ out) {
  const int b = blockIdx.x;
  const int t = threadIdx.x;
  const int wv = t >> 6;
  const int lane = t & 63;
  __shared__ float sc[20];
  __shared__ float ctxp[4][128];
  const float2 qv = ((const float2*)(Qm + b * 128))[lane];
  const float2 bvv = ((const float2*)bv)[lane];
  const float* gr[5];
  float2 V[5];
  #pragma unroll
  for (int j = 0; j < 5; ++j) {
    const unsigned long long cell = cells[b * 20 + wv * 5 + j];
    const int n = 32767 - (int)(cell & 0x7FFFull);
    gr[j] = ge + (size_t)n * 256;
    V[j] = bvv;
  }
  for (int f = 0; f < 256; f += 4) {
    const float2 w0 = ((const float2*)(Wv + (size_t)(f + 0) * 128))[lane];
    const float2 w1 = ((const float2*)(Wv + (size_t)(f + 1) * 128))[lane];
    const float2 w2_ = ((const float2*)(Wv + (size_t)(f + 2) * 128))[lane];
    const float2 w3 = ((const float2*)(Wv + (size_t)(f + 3) * 128))[lane];
    #pragma unroll
    for (int j = 0; j < 5; ++j) {
      const float4 gv = *(const float4*)(gr[j] + f);   // uniform -> s_load
      V[j].x = fmaf(gv.x, w0.x, V[j].x); V[j].y = fmaf(gv.x, w0.y, V[j].y);
      V[j].x = fmaf(gv.y, w1.x, V[j].x); V[j].y = fmaf(gv.y, w1.y, V[j].y);
      V[j].x = fmaf(gv.z, w2_.x, V[j].x); V[j].y = fmaf(gv.z, w2_.y, V[j].y);
      V[j].x = fmaf(gv.w, w3.x, V[j].x); V[j].y = fmaf(gv.w, w3.y, V[j].y);
    }
  }
  #pragma unroll
  for (int j = 0; j < 5; ++j) {
    float pr = qv.x * V[j].x + qv.y * V[j].y;
    #pragma unroll
    for (int off = 32; off; off >>= 1) pr += __shfl_xor(pr, off, 64);
    if (lane == 0) sc[wv * 5 + j] = pr * 0.08838834764831845f;  // 1/sqrt(128)
  }
  __syncthreads();
  float m = -3.0e38f;
  #pragma unroll
  for (int i = 0; i < 20; ++i) m = fmaxf(m, sc[i]);
  float s = 0.f;
  #pragma unroll
  for (int i = 0; i < 20; ++i) s += expf(sc[i] - m);
  const float inv = 1.0f / s;
  float c0 = 0.f, c1 = 0.f;
  #pragma unroll
  for (int j = 0; j < 5; ++j) {
    const float wk = expf(sc[wv * 5 + j] - m) * inv;
    c0 = fmaf(wk, V[j].x, c0);
    c1 = fmaf(wk, V[j].y, c1);
  }
  ctxp[wv][2 * lane] = c0;
  ctxp[wv][2 * lane + 1] = c1;
  __syncthreads();
  if (t < 128)
    out[b * 128 + t] = (ctxp[0][t] + ctxp[1][t]) + (ctxp[2][t] + ctxp[3][t]);
}

extern "C" void kernel_launch(void* const* d_in, const int* in_sizes, int n_in,
                              void* d_out, int out_size, void* d_ws, size_t ws_size,
                              hipStream_t stream) {
  (void)in_sizes; (void)n_in; (void)out_size; (void)ws_size;
  const float* pe = (const float*)d_in[0];
  const float* ge = (const float*)d_in[1];
  const float* Wq = (const float*)d_in[2];
  const float* bq = (const float*)d_in[3];
  const float* Wk = (const float*)d_in[4];
  const float* bk = (const float*)d_in[5];
  const float* Wv = (const float*)d_in[6];
  const float* bvp = (const float*)d_in[7];
  const float* W1 = (const float*)d_in[8];
  const float* b1 = (const float*)d_in[9];
  const float* w2 = (const float*)d_in[10];
  // d_in[11] = b2: uniform over n -> cancels in argmax; absent from output path.

  char* w = (char*)d_ws;
  float* Wf32 = (float*)w;                               // 131072 B
  double* qbT = (double*)(w + 131072);                   // 65536 B
  float* Qm = (float*)(w + 196608);                      // 32768 B
  unsigned long long* cells =
      (unsigned long long*)(w + 229376);                 // 10240 B
  double2* c12 = (double2*)(w + 239616);                 // 2048 B (~0.24 MB total)
  float* out = (float*)d_out;

  kprep<<<dim3(321), dim3(128), 0, stream>>>(pe, Wq, bq, Wk, bk, W1, b1, w2,
                                             Wf32, qbT, Qm, cells, c12);
  kfused<<<dim3(2500), dim3(256), 0, stream>>>(ge, Wf32, qbT, c12, cells);
  kfinal<<<dim3(64), dim3(256), 0, stream>>>(ge, Wv, bvp, Qm, cells, out);
}

// Round 3
// 278.697 us; speedup vs baseline: 1.1681x; 1.1681x over previous
//
#include <hip/hip_runtime.h>

#define NG 20000

// single-instruction rotate (v_alignbit_b32): rotl(x,r) == alignbit(x,x,32-r)
__device__ __forceinline__ unsigned rotl32(unsigned x, int r) {
  return __builtin_amdgcn_alignbit(x, x, 32 - r);
}

// ---------- JAX threefry2x32, key = (0, 42) ----------
__device__ __forceinline__ void threefry2x32(unsigned x0, unsigned x1,
                                             unsigned& o0, unsigned& o1) {
  const unsigned ks0 = 0u;
  const unsigned ks1 = 42u;
  const unsigned ks2 = 0x1BD11BDAu ^ 0u ^ 42u;
  x0 += ks0; x1 += ks1;
#define TFR(r) { x0 += x1; x1 = rotl32(x1, (r)); x1 ^= x0; }
  TFR(13) TFR(15) TFR(26) TFR(6)
  x0 += ks1; x1 += ks2 + 1u;
  TFR(17) TFR(29) TFR(16) TFR(24)
  x0 += ks2; x1 += ks0 + 2u;
  TFR(13) TFR(15) TFR(26) TFR(6)
  x0 += ks0; x1 += ks1 + 3u;
  TFR(17) TFR(29) TFR(16) TFR(24)
  x0 += ks1; x1 += ks2 + 4u;
  TFR(13) TFR(15) TFR(26) TFR(6)
  x0 += ks2; x1 += ks0 + 5u;
#undef TFR
  o0 = x0; o1 = x1;
}

// JAX threefry_partitionable: bits(i) = o0 ^ o1 of threefry((0,42),(0,i))
__device__ __forceinline__ unsigned tfbits(unsigned ctr) {
  unsigned o0, o1;
  threefry2x32(0u, ctr, o0, o1);
  return o0 ^ o1;
}

// fp32 fast-screen gumbel, constant-folded: g = -ln2*log2(-log2(u)) - ln(ln2)
__device__ __forceinline__ float gumbel32(unsigned bits) {
  float f = __uint_as_float((bits >> 9) | 0x3f800000u) - 1.0f;
  float u = fmaxf(f, 1.17549435e-38f);
  const float l2u = __log2f(u);                     // strictly < 0
  return fmaf(-0.69314718056f, __log2f(-l2u), 0.3665129206f);
}

// exact fp64 gumbel; u is a 23-bit dyadic rational, exact in double
__device__ __forceinline__ double gumbel64(unsigned bits) {
  float f = __uint_as_float((bits >> 9) | 0x3f800000u) - 1.0f;
  double u = (double)fmaxf(f, 1.17549435e-38f);
  return -log(-log(u));
}

// pack fp64 score (top 49 monotone bits) + 15-bit (32767-n): u64 max == (score, then smaller n)
__device__ __forceinline__ unsigned long long packcell(double v, int n) {
  unsigned long long u = (unsigned long long)__double_as_longlong(v);
  u = (u >> 63) ? ~u : (u | 0x8000000000000000ull);
  return (u & 0xFFFFFFFFFFFF8000ull) | (unsigned long long)(32767 - n);
}

// monotone fp32 pack (high 32) + gene index (low 32) for top-2 reduction
__device__ __forceinline__ unsigned long long packscreen(float v, int n) {
  unsigned u = __float_as_uint(v);
  u = (u >> 31) ? ~u : (u | 0x80000000u);
  return ((unsigned long long)u << 32) | (unsigned)n;
}

// ---------- prep: Wf=Wk@W1k (fp64 math, fp32 store), Q, qbT; c12; zero cells ----------
__global__ __launch_bounds__(128) void kprep(
    const float* __restrict__ pe, const float* __restrict__ Wq,
    const float* __restrict__ bq, const float* __restrict__ Wk,
    const float* __restrict__ bk, const float* __restrict__ W1,
    const float* __restrict__ b1, const float* __restrict__ w2,
    float* __restrict__ Wf32, double* __restrict__ qbT,
    float* __restrict__ Qm, unsigned long long* __restrict__ cells,
    double2* __restrict__ c12) {
  __shared__ float L[512];
  __shared__ double Ld[128];
  const int t = threadIdx.x;
  const int bid = blockIdx.x;
  if (bid < 256) {
    L[t] = Wk[bid * 128 + t];
    __syncthreads();
    double acc = 0.0;
    #pragma unroll 16
    for (int j = 0; j < 128; ++j)
      acc = fma((double)L[j], (double)W1[(128 + j) * 128 + t], acc);
    Wf32[bid * 128 + t] = (float)acc;
  } else if (bid < 320) {
    const int b = bid - 256;
    #pragma unroll
    for (int i = 0; i < 4; ++i) L[t + 128 * i] = pe[b * 512 + t + 128 * i];
    __syncthreads();
    double q = (double)bq[t];
    #pragma unroll 16
    for (int f = 0; f < 512; ++f)
      q = fma((double)L[f], (double)Wq[f * 128 + t], q);
    Qm[b * 128 + t] = (float)q;   // epilogue path stays fp32
    Ld[t] = q;
    __syncthreads();
    // qb[b,d=t] = Q@W1[:128] + b1 + bk@W1[128:]; store transposed qbT[d][b]
    double acc = (double)b1[t];
    #pragma unroll 8
    for (int j = 0; j < 128; ++j) {
      acc = fma(Ld[j], (double)W1[j * 128 + t], acc);
      acc = fma((double)bk[j], (double)W1[(128 + j) * 128 + t], acc);
    }
    qbT[t * 64 + b] = acc;
  } else {
    for (int i = t; i < 1280; i += 128) cells[i] = 0ull;
    const double w2d = (double)w2[t];
    c12[t] = make_double2(0.55 * w2d, 0.45 * w2d);
  }
}

// ---------- ksim: kp(fp32 GEMM) + sim(fp64) -> simg[64][20000] (NO atomics) ----------
// R0's proven 16-gene geometry (1250 blocks x 256 thr). Phase 1: wave wv owns
// genes wv*4..wv*4+3; thread owns d = {2*lane, 2*lane+1} (float2 W-stream); ge
// tile in LDS (broadcast ds_read_b128), Wf32 depth-2 register stream. Per-acc
// f ascending -> kp bit-identical. Phase 2: fp64 sim, wave wv computes genes
// {wv,wv+4,wv+8,wv+12}, lane = batch; identical fp64 op order. Then transpose
// simLf via LDS and store coalesced float4 to simg.
__global__ __launch_bounds__(256) void ksim(
    const float* __restrict__ ge, const float* __restrict__ Wf32,
    const double* __restrict__ qbT, const double2* __restrict__ c12,
    float* __restrict__ simg) {
  __shared__ double SBd[2048];   // phase1: geL (16 KB as float); phase2: simLf
  __shared__ float kpL[2048];    // kp[16][128]
  float* geL = (float*)SBd;
  float* simLf = (float*)SBd;    // [64][17]
  const int t = threadIdx.x;
  const int wv = t >> 6;
  const int lane = t & 63;
  const int g0 = blockIdx.x * 16;     // 1250 blocks * 16 genes

  // stage ge tile (16 genes x 256 f) -> LDS: 4 independent float4 per thread
  {
    const float4* src = (const float4*)(ge + (size_t)g0 * 256);
    float4* dst = (float4*)geL;
    #pragma unroll
    for (int i = 0; i < 4; ++i) dst[t + i * 256] = src[t + i * 256];
  }
  __syncthreads();

  // ---- phase 1: fp32 GEMM from LDS genes + streamed Wf32 (float2 over d) ----
  float acc[4][2];
  #pragma unroll
  for (int j = 0; j < 4; ++j) { acc[j][0] = 0.f; acc[j][1] = 0.f; }
  const float2* wb = (const float2*)Wf32 + lane;   // element f*64+lane -> d {2l,2l+1}
  const float* gL = geL + wv * 4 * 256;

  float2 wc[4];
  #pragma unroll
  for (int ff = 0; ff < 4; ++ff) wc[ff] = wb[ff * 64];
  for (int f0 = 0; f0 < 256; f0 += 4) {
    float2 wn[4];
    if (f0 < 252) {
      #pragma unroll
      for (int ff = 0; ff < 4; ++ff) wn[ff] = wb[(f0 + 4 + ff) * 64];
    }
    #pragma unroll
    for (int j = 0; j < 4; ++j) {
      const float4 gv = *(const float4*)(gL + j * 256 + f0);  // ds_read_b128 bcast
      acc[j][0] = fmaf(gv.x, wc[0].x, acc[j][0]);
      acc[j][1] = fmaf(gv.x, wc[0].y, acc[j][1]);
      acc[j][0] = fmaf(gv.y, wc[1].x, acc[j][0]);
      acc[j][1] = fmaf(gv.y, wc[1].y, acc[j][1]);
      acc[j][0] = fmaf(gv.z, wc[2].x, acc[j][0]);
      acc[j][1] = fmaf(gv.z, wc[2].y, acc[j][1]);
      acc[j][0] = fmaf(gv.w, wc[3].x, acc[j][0]);
      acc[j][1] = fmaf(gv.w, wc[3].y, acc[j][1]);
    }
    #pragma unroll
    for (int ff = 0; ff < 4; ++ff) wc[ff] = wn[ff];
  }

  __syncthreads();   // geL reads done (SBd about to be reused as simLf)
  #pragma unroll
  for (int j = 0; j < 4; ++j)
    ((float2*)(kpL + (wv * 4 + j) * 128))[lane] =
        make_float2(acc[j][0], acc[j][1]);
  __syncthreads();

  // ---- phase 2: fp64 sim (4 genes/wave, lane = batch) ----
  double s[4];
  #pragma unroll
  for (int j = 0; j < 4; ++j) s[j] = 0.0;
  for (int dd = 0; dd < 128; ++dd) {
    const double2 cc = c12[dd];                   // uniform -> s_load
    const double qv = qbT[dd * 64 + lane];        // coalesced, L1-hot
    #pragma unroll
    for (int j = 0; j < 4; ++j) {
      const double kv = (double)kpL[(wv + j * 4) * 128 + dd];  // broadcast
      const double tt = qv + kv;
      s[j] = fma(tt, cc.x, s[j]);
      s[j] = fma(fabs(tt), cc.y, s[j]);
    }
  }
  #pragma unroll
  for (int j = 0; j < 4; ++j)
    simLf[lane * 17 + (wv + j * 4)] = (float)(2.0 * s[j]);
  __syncthreads();

  // ---- transpose-store: thread t -> b = t>>2, gene-chunk = t&3 (float4) ----
  {
    const int b = t >> 2;
    const int gc = t & 3;
    float4 v;
    v.x = simLf[b * 17 + gc * 4 + 0];
    v.y = simLf[b * 17 + gc * 4 + 1];
    v.z = simLf[b * 17 + gc * 4 + 2];
    v.w = simLf[b * 17 + gc * 4 + 3];
    *(float4*)(simg + (size_t)b * NG + g0 + gc * 4) = v;
  }
}

// ---------- kargmax: one block per cell, full-row screen, single writer ----------
// 1280 blocks x 256 thr. Thread scans n = t, t+256, ... (coalesced, L2/L3-hot
// sim row), fp32 top-2 per thread; packed-u64 top-2 wave butterfly; cross-wave
// merge in LDS; thread 0 fp64-exact winner (+ runner-up iff fp32 gap < 1e-4,
// same screen-error policy: err 2e-5 << 1e-4) -> plain store. No atomics.
__global__ __launch_bounds__(256) void kargmax(
    const float* __restrict__ simg, unsigned long long* __restrict__ cells) {
  __shared__ unsigned long long R1s[4], R2s[4];
  const int cell = blockIdx.x;                 // = b*20 + k
  const int t = threadIdx.x;
  const int wv = t >> 6;
  const int lane = t & 63;
  const int b = (unsigned)cell / 20u;
  const float* sb = simg + (size_t)b * NG;
  const unsigned ib = (unsigned)cell * (unsigned)NG;

  float m1 = -3e38f, m2 = -3e38f;
  int n1 = -1, n2 = -1;
  for (int n = t; n < NG; n += 256) {
    const unsigned bb = tfbits(ib + (unsigned)n);
    const float sc = sb[n] + gumbel32(bb);
    if (sc > m1) { m2 = m1; n2 = n1; m1 = sc; n1 = n; }
    else if (sc > m2) { m2 = sc; n2 = n; }
  }
  unsigned long long p1 = packscreen(m1, n1);
  unsigned long long p2 = packscreen(m2, n2);
  // wave top-2 butterfly: merge sorted pairs (p1>=p2), (q1>=q2)
  #pragma unroll
  for (int off = 32; off; off >>= 1) {
    unsigned long long q1 = __shfl_xor(p1, off, 64);
    unsigned long long q2 = __shfl_xor(p2, off, 64);
    if (q1 > p1) {
      unsigned long long t1 = p1;
      p1 = q1;
      p2 = (q2 > t1) ? q2 : t1;
    } else {
      p2 = (q1 > p2) ? q1 : p2;
    }
  }
  if (lane == 0) { R1s[wv] = p1; R2s[wv] = p2; }
  __syncthreads();
  if (t == 0) {
    unsigned long long P1 = R1s[0], P2 = R2s[0];
    #pragma unroll
    for (int w = 1; w < 4; ++w) {
      unsigned long long q1 = R1s[w], q2 = R2s[w];
      if (q1 > P1) {
        unsigned long long t1 = P1;
        P1 = q1;
        P2 = (q2 > t1) ? q2 : t1;
      } else {
        P2 = (q1 > P2) ? q1 : P2;
      }
    }
    const int w1 = (int)(P1 & 0xFFFFFFFFull);
    const int w2i = (int)(P2 & 0xFFFFFFFFull);
    const unsigned bb1 = tfbits(ib + (unsigned)w1);
    const float s1f = sb[w1];
    const float sc1 = s1f + gumbel32(bb1);
    unsigned long long pb = packcell((double)s1f + gumbel64(bb1), w1);
    if (w2i >= 0) {
      const unsigned bb2 = tfbits(ib + (unsigned)w2i);
      const float s2f = sb[w2i];
      const float sc2 = s2f + gumbel32(bb2);
      if ((sc1 - sc2) < 1e-4f) {
        const unsigned long long u2 =
            packcell((double)s2f + gumbel64(bb2), w2i);
        if (u2 > pb) pb = u2;
      }
    }
    cells[cell] = pb;
  }
}

// ---------- epilogue (fp32): 5 interleaved V-GEMVs per wave, softmax over K, context ----------
__global__ __launch_bounds__(256) void kfinal(
    const float* __restrict__ ge, const float* __restrict__ Wv,
    const float* __restrict__ bv, const float* __restrict__ Qm,
    const unsigned long long* __restrict__ cells, float* __restrict__ out) {
  const int b = blockIdx.x;
  const int t = threadIdx.x;
  const int wv = t >> 6;
  const int lane = t & 63;
  __shared__ float sc[20];
  __shared__ float ctxp[4][128];
  const float2 qv = ((const float2*)(Qm + b * 128))[lane];
  const float2 bvv = ((const float2*)bv)[lane];
  const float* gr[5];
  float2 V[5];
  #pragma unroll
  for (int j = 0; j < 5; ++j) {
    const unsigned long long cell = cells[b * 20 + wv * 5 + j];
    const int n = 32767 - (int)(cell & 0x7FFFull);
    gr[j] = ge + (size_t)n * 256;
    V[j] = bvv;
  }
  for (int f = 0; f < 256; f += 4) {
    const float2 w0 = ((const float2*)(Wv + (size_t)(f + 0) * 128))[lane];
    const float2 w1 = ((const float2*)(Wv + (size_t)(f + 1) * 128))[lane];
    const float2 w2_ = ((const float2*)(Wv + (size_t)(f + 2) * 128))[lane];
    const float2 w3 = ((const float2*)(Wv + (size_t)(f + 3) * 128))[lane];
    #pragma unroll
    for (int j = 0; j < 5; ++j) {
      const float4 gv = *(const float4*)(gr[j] + f);   // uniform -> s_load
      V[j].x = fmaf(gv.x, w0.x, V[j].x); V[j].y = fmaf(gv.x, w0.y, V[j].y);
      V[j].x = fmaf(gv.y, w1.x, V[j].x); V[j].y = fmaf(gv.y, w1.y, V[j].y);
      V[j].x = fmaf(gv.z, w2_.x, V[j].x); V[j].y = fmaf(gv.z, w2_.y, V[j].y);
      V[j].x = fmaf(gv.w, w3.x, V[j].x); V[j].y = fmaf(gv.w, w3.y, V[j].y);
    }
  }
  #pragma unroll
  for (int j = 0; j < 5; ++j) {
    float pr = qv.x * V[j].x + qv.y * V[j].y;
    #pragma unroll
    for (int off = 32; off; off >>= 1) pr += __shfl_xor(pr, off, 64);
    if (lane == 0) sc[wv * 5 + j] = pr * 0.08838834764831845f;  // 1/sqrt(128)
  }
  __syncthreads();
  float m = -3.0e38f;
  #pragma unroll
  for (int i = 0; i < 20; ++i) m = fmaxf(m, sc[i]);
  float s = 0.f;
  #pragma unroll
  for (int i = 0; i < 20; ++i) s += expf(sc[i] - m);
  const float inv = 1.0f / s;
  float c0 = 0.f, c1 = 0.f;
  #pragma unroll
  for (int j = 0; j < 5; ++j) {
    const float wk = expf(sc[wv * 5 + j] - m) * inv;
    c0 = fmaf(wk, V[j].x, c0);
    c1 = fmaf(wk, V[j].y, c1);
  }
  ctxp[wv][2 * lane] = c0;
  ctxp[wv][2 * lane + 1] = c1;
  __syncthreads();
  if (t < 128)
    out[b * 128 + t] = (ctxp[0][t] + ctxp[1][t]) + (ctxp[2][t] + ctxp[3][t]);
}

extern "C" void kernel_launch(void* const* d_in, const int* in_sizes, int n_in,
                              void* d_out, int out_size, void* d_ws, size_t ws_size,
                              hipStream_t stream) {
  (void)in_sizes; (void)n_in; (void)out_size; (void)ws_size;
  const float* pe = (const float*)d_in[0];
  const float* ge = (const float*)d_in[1];
  const float* Wq = (const float*)d_in[2];
  const float* bq = (const float*)d_in[3];
  const float* Wk = (const float*)d_in[4];
  const float* bk = (const float*)d_in[5];
  const float* Wv = (const float*)d_in[6];
  const float* bvp = (const float*)d_in[7];
  const float* W1 = (const float*)d_in[8];
  const float* b1 = (const float*)d_in[9];
  const float* w2 = (const float*)d_in[10];
  // d_in[11] = b2: uniform over n -> cancels in argmax; absent from output path.

  char* w = (char*)d_ws;
  float* Wf32 = (float*)w;                               // 131072 B
  double* qbT = (double*)(w + 131072);                   // 65536 B
  float* Qm = (float*)(w + 196608);                      // 32768 B
  unsigned long long* cells =
      (unsigned long long*)(w + 229376);                 // 10240 B
  double2* c12 = (double2*)(w + 239616);                 // 2048 B
  float* simg = (float*)(w + 262144);                    // 5,120,000 B (~5.4 MB total)
  float* out = (float*)d_out;

  kprep<<<dim3(321), dim3(128), 0, stream>>>(pe, Wq, bq, Wk, bk, W1, b1, w2,
                                             Wf32, qbT, Qm, cells, c12);
  ksim<<<dim3(1250), dim3(256), 0, stream>>>(ge, Wf32, qbT, c12, simg);
  kargmax<<<dim3(1280), dim3(256), 0, stream>>>(simg, cells);
  kfinal<<<dim3(64), dim3(256), 0, stream>>>(ge, Wv, bvp, Qm, cells, out);
}

// Round 4
// 272.627 us; speedup vs baseline: 1.1941x; 1.0223x over previous
//
#include <hip/hip_runtime.h>

#define NG 20000

// single-instruction rotate (v_alignbit_b32): rotl(x,r) == alignbit(x,x,32-r)
__device__ __forceinline__ unsigned rotl32(unsigned x, int r) {
  return __builtin_amdgcn_alignbit(x, x, 32 - r);
}

// ---------- JAX threefry2x32, key = (0, 42) ----------
__device__ __forceinline__ void threefry2x32(unsigned x0, unsigned x1,
                                             unsigned& o0, unsigned& o1) {
  const unsigned ks0 = 0u;
  const unsigned ks1 = 42u;
  const unsigned ks2 = 0x1BD11BDAu ^ 0u ^ 42u;
  x0 += ks0; x1 += ks1;
#define TFR(r) { x0 += x1; x1 = rotl32(x1, (r)); x1 ^= x0; }
  TFR(13) TFR(15) TFR(26) TFR(6)
  x0 += ks1; x1 += ks2 + 1u;
  TFR(17) TFR(29) TFR(16) TFR(24)
  x0 += ks2; x1 += ks0 + 2u;
  TFR(13) TFR(15) TFR(26) TFR(6)
  x0 += ks0; x1 += ks1 + 3u;
  TFR(17) TFR(29) TFR(16) TFR(24)
  x0 += ks1; x1 += ks2 + 4u;
  TFR(13) TFR(15) TFR(26) TFR(6)
  x0 += ks2; x1 += ks0 + 5u;
#undef TFR
  o0 = x0; o1 = x1;
}

// JAX threefry_partitionable: bits(i) = o0 ^ o1 of threefry((0,42),(0,i))
__device__ __forceinline__ unsigned tfbits(unsigned ctr) {
  unsigned o0, o1;
  threefry2x32(0u, ctr, o0, o1);
  return o0 ^ o1;
}

// fp32 fast-screen gumbel, constant-folded: g = -ln2*log2(-log2(u)) - ln(ln2)
__device__ __forceinline__ float gumbel32(unsigned bits) {
  float f = __uint_as_float((bits >> 9) | 0x3f800000u) - 1.0f;
  float u = fmaxf(f, 1.17549435e-38f);
  const float l2u = __log2f(u);                     // strictly < 0
  return fmaf(-0.69314718056f, __log2f(-l2u), 0.3665129206f);
}

// exact fp64 gumbel; u is a 23-bit dyadic rational, exact in double
__device__ __forceinline__ double gumbel64(unsigned bits) {
  float f = __uint_as_float((bits >> 9) | 0x3f800000u) - 1.0f;
  double u = (double)fmaxf(f, 1.17549435e-38f);
  return -log(-log(u));
}

// pack fp64 score (top 49 monotone bits) + 15-bit (32767-n): u64 max == (score, then smaller n)
__device__ __forceinline__ unsigned long long packcell(double v, int n) {
  unsigned long long u = (unsigned long long)__double_as_longlong(v);
  u = (u >> 63) ? ~u : (u | 0x8000000000000000ull);
  return (u & 0xFFFFFFFFFFFF8000ull) | (unsigned long long)(32767 - n);
}

// monotone fp32 pack (high 32) + gene index (low 32) for top-2 reduction
__device__ __forceinline__ unsigned long long packscreen(float v, int n) {
  unsigned u = __float_as_uint(v);
  u = (u >> 31) ? ~u : (u | 0x80000000u);
  return ((unsigned long long)u << 32) | (unsigned)n;
}

// ---------- prep: Wf=Wk@W1k (fp64 math, fp32 store), Q, qbT; c12; zero cells ----------
__global__ __launch_bounds__(128) void kprep(
    const float* __restrict__ pe, const float* __restrict__ Wq,
    const float* __restrict__ bq, const float* __restrict__ Wk,
    const float* __restrict__ bk, const float* __restrict__ W1,
    const float* __restrict__ b1, const float* __restrict__ w2,
    float* __restrict__ Wf32, double* __restrict__ qbT,
    float* __restrict__ Qm, unsigned long long* __restrict__ cells,
    double2* __restrict__ c12) {
  __shared__ float L[512];
  __shared__ double Ld[128];
  const int t = threadIdx.x;
  const int bid = blockIdx.x;
  if (bid < 256) {
    L[t] = Wk[bid * 128 + t];
    __syncthreads();
    double acc = 0.0;
    #pragma unroll 16
    for (int j = 0; j < 128; ++j)
      acc = fma((double)L[j], (double)W1[(128 + j) * 128 + t], acc);
    Wf32[bid * 128 + t] = (float)acc;
  } else if (bid < 320) {
    const int b = bid - 256;
    #pragma unroll
    for (int i = 0; i < 4; ++i) L[t + 128 * i] = pe[b * 512 + t + 128 * i];
    __syncthreads();
    double q = (double)bq[t];
    #pragma unroll 16
    for (int f = 0; f < 512; ++f)
      q = fma((double)L[f], (double)Wq[f * 128 + t], q);
    Qm[b * 128 + t] = (float)q;   // epilogue path stays fp32
    Ld[t] = q;
    __syncthreads();
    // qb[b,d=t] = Q@W1[:128] + b1 + bk@W1[128:]; store transposed qbT[d][b]
    double acc = (double)b1[t];
    #pragma unroll 8
    for (int j = 0; j < 128; ++j) {
      acc = fma(Ld[j], (double)W1[j * 128 + t], acc);
      acc = fma((double)bk[j], (double)W1[(128 + j) * 128 + t], acc);
    }
    qbT[t * 64 + b] = acc;
  } else {
    for (int i = t; i < 1280; i += 128) cells[i] = 0ull;
    const double w2d = (double)w2[t];
    c12[t] = make_double2(0.55 * w2d, 0.45 * w2d);
  }
}

// ---------- ksim: kp(fp32 GEMM) + sim(fp64) -> simg[64][20000] (NO atomics) ----------
// R0's proven 16-gene geometry (1250 blocks x 256 thr). Phase 1: wave wv owns
// genes wv*4..wv*4+3; thread owns d = {2*lane, 2*lane+1} (float2 W-stream); ge
// tile in LDS (broadcast ds_read_b128), Wf32 depth-2 register stream. Per-acc
// f ascending -> kp bit-identical. Phase 2: fp64 sim, wave wv computes genes
// {wv,wv+4,wv+8,wv+12}, lane = batch; identical fp64 op order. Then transpose
// simLf via LDS and store coalesced float4 to simg.
__global__ __launch_bounds__(256) void ksim(
    const float* __restrict__ ge, const float* __restrict__ Wf32,
    const double* __restrict__ qbT, const double2* __restrict__ c12,
    float* __restrict__ simg) {
  __shared__ double SBd[2048];   // phase1: geL (16 KB as float); phase2: simLf
  __shared__ float kpL[2048];    // kp[16][128]
  float* geL = (float*)SBd;
  float* simLf = (float*)SBd;    // [64][17]
  const int t = threadIdx.x;
  const int wv = t >> 6;
  const int lane = t & 63;
  const int g0 = blockIdx.x * 16;     // 1250 blocks * 16 genes

  // stage ge tile (16 genes x 256 f) -> LDS: 4 independent float4 per thread
  {
    const float4* src = (const float4*)(ge + (size_t)g0 * 256);
    float4* dst = (float4*)geL;
    #pragma unroll
    for (int i = 0; i < 4; ++i) dst[t + i * 256] = src[t + i * 256];
  }
  __syncthreads();

  // ---- phase 1: fp32 GEMM from LDS genes + streamed Wf32 (float2 over d) ----
  float acc[4][2];
  #pragma unroll
  for (int j = 0; j < 4; ++j) { acc[j][0] = 0.f; acc[j][1] = 0.f; }
  const float2* wb = (const float2*)Wf32 + lane;   // element f*64+lane -> d {2l,2l+1}
  const float* gL = geL + wv * 4 * 256;

  float2 wc[4];
  #pragma unroll
  for (int ff = 0; ff < 4; ++ff) wc[ff] = wb[ff * 64];
  for (int f0 = 0; f0 < 256; f0 += 4) {
    float2 wn[4];
    if (f0 < 252) {
      #pragma unroll
      for (int ff = 0; ff < 4; ++ff) wn[ff] = wb[(f0 + 4 + ff) * 64];
    }
    #pragma unroll
    for (int j = 0; j < 4; ++j) {
      const float4 gv = *(const float4*)(gL + j * 256 + f0);  // ds_read_b128 bcast
      acc[j][0] = fmaf(gv.x, wc[0].x, acc[j][0]);
      acc[j][1] = fmaf(gv.x, wc[0].y, acc[j][1]);
      acc[j][0] = fmaf(gv.y, wc[1].x, acc[j][0]);
      acc[j][1] = fmaf(gv.y, wc[1].y, acc[j][1]);
      acc[j][0] = fmaf(gv.z, wc[2].x, acc[j][0]);
      acc[j][1] = fmaf(gv.z, wc[2].y, acc[j][1]);
      acc[j][0] = fmaf(gv.w, wc[3].x, acc[j][0]);
      acc[j][1] = fmaf(gv.w, wc[3].y, acc[j][1]);
    }
    #pragma unroll
    for (int ff = 0; ff < 4; ++ff) wc[ff] = wn[ff];
  }

  __syncthreads();   // geL reads done (SBd about to be reused as simLf)
  #pragma unroll
  for (int j = 0; j < 4; ++j)
    ((float2*)(kpL + (wv * 4 + j) * 128))[lane] =
        make_float2(acc[j][0], acc[j][1]);
  __syncthreads();

  // ---- phase 2: fp64 sim (4 genes/wave, lane = batch) ----
  double s[4];
  #pragma unroll
  for (int j = 0; j < 4; ++j) s[j] = 0.0;
  for (int dd = 0; dd < 128; ++dd) {
    const double2 cc = c12[dd];                   // uniform -> s_load
    const double qv = qbT[dd * 64 + lane];        // coalesced, L1-hot
    #pragma unroll
    for (int j = 0; j < 4; ++j) {
      const double kv = (double)kpL[(wv + j * 4) * 128 + dd];  // broadcast
      const double tt = qv + kv;
      s[j] = fma(tt, cc.x, s[j]);
      s[j] = fma(fabs(tt), cc.y, s[j]);
    }
  }
  #pragma unroll
  for (int j = 0; j < 4; ++j)
    simLf[lane * 17 + (wv + j * 4)] = (float)(2.0 * s[j]);
  __syncthreads();

  // ---- transpose-store: thread t -> b = t>>2, gene-chunk = t&3 (float4) ----
  {
    const int b = t >> 2;
    const int gc = t & 3;
    float4 v;
    v.x = simLf[b * 17 + gc * 4 + 0];
    v.y = simLf[b * 17 + gc * 4 + 1];
    v.z = simLf[b * 17 + gc * 4 + 2];
    v.w = simLf[b * 17 + gc * 4 + 3];
    *(float4*)(simg + (size_t)b * NG + g0 + gc * 4) = v;
  }
}

// ---------- kargmax: 2 windows per cell, pairwise-ILP screen, atomicMax merge ----------
// 2560 blocks x 256 thr (10 blocks/CU supply -> occupancy at the 8-block HW cap,
// vs 5 blocks/CU = 35% in R3). Block = (cell, window); window = 10000 genes.
// Inner loop processes gene pairs (n, n+256): two independent threefry chains
// interleave in the issue slots (threefry is a serial x0<->x1 dep chain, ILP~1
// alone). fp32 top-2 per thread; packed-u64 top-2 wave butterfly; cross-wave
// LDS merge; thread 0 fp64-exact window winner (+ runner-up iff fp32 gap <
// 1e-4, screen err 2e-5 << margin) -> ONE atomicMax per window (2 writers/cell,
// 2560 total: contention-free by construction; cells zeroed by kprep).
// Max of exact window winners == exact global argmax (window-size-independent).
__global__ __launch_bounds__(256) void kargmax(
    const float* __restrict__ simg, unsigned long long* __restrict__ cells) {
  __shared__ unsigned long long R1s[4], R2s[4];
  const int cell = blockIdx.x >> 1;            // = b*20 + k
  const int wdw = blockIdx.x & 1;
  const int t = threadIdx.x;
  const int wv = t >> 6;
  const int lane = t & 63;
  const int b = (unsigned)cell / 20u;
  const float* sb = simg + (size_t)b * NG;
  const unsigned ib = (unsigned)cell * (unsigned)NG;
  const int base = wdw * 10000;
  const int end = base + 10000;

  float m1 = -3e38f, m2 = -3e38f;
  int n1 = -1, n2 = -1;
  int n = base + t;
  // pair loop: candidates n and n+256 (independent threefry chains -> ILP 2)
  for (; n + 256 < end; n += 512) {
    const unsigned bbA = tfbits(ib + (unsigned)n);
    const unsigned bbB = tfbits(ib + (unsigned)(n + 256));
    const float sA = sb[n] + gumbel32(bbA);
    const float sB = sb[n + 256] + gumbel32(bbB);
    if (sA > m1) { m2 = m1; n2 = n1; m1 = sA; n1 = n; }
    else if (sA > m2) { m2 = sA; n2 = n; }
    if (sB > m1) { m2 = m1; n2 = n1; m1 = sB; n1 = n + 256; }
    else if (sB > m2) { m2 = sB; n2 = n + 256; }
  }
  for (; n < end; n += 256) {
    const unsigned bb = tfbits(ib + (unsigned)n);
    const float sc = sb[n] + gumbel32(bb);
    if (sc > m1) { m2 = m1; n2 = n1; m1 = sc; n1 = n; }
    else if (sc > m2) { m2 = sc; n2 = n; }
  }
  unsigned long long p1 = packscreen(m1, n1);
  unsigned long long p2 = packscreen(m2, n2);
  // wave top-2 butterfly: merge sorted pairs (p1>=p2), (q1>=q2)
  #pragma unroll
  for (int off = 32; off; off >>= 1) {
    unsigned long long q1 = __shfl_xor(p1, off, 64);
    unsigned long long q2 = __shfl_xor(p2, off, 64);
    if (q1 > p1) {
      unsigned long long t1 = p1;
      p1 = q1;
      p2 = (q2 > t1) ? q2 : t1;
    } else {
      p2 = (q1 > p2) ? q1 : p2;
    }
  }
  if (lane == 0) { R1s[wv] = p1; R2s[wv] = p2; }
  __syncthreads();
  if (t == 0) {
    unsigned long long P1 = R1s[0], P2 = R2s[0];
    #pragma unroll
    for (int w = 1; w < 4; ++w) {
      unsigned long long q1 = R1s[w], q2 = R2s[w];
      if (q1 > P1) {
        unsigned long long t1 = P1;
        P1 = q1;
        P2 = (q2 > t1) ? q2 : t1;
      } else {
        P2 = (q1 > P2) ? q1 : P2;
      }
    }
    const int w1 = (int)(P1 & 0xFFFFFFFFull);
    const int w2i = (int)(P2 & 0xFFFFFFFFull);
    const unsigned bb1 = tfbits(ib + (unsigned)w1);
    const float s1f = sb[w1];
    const float sc1 = s1f + gumbel32(bb1);
    unsigned long long pb = packcell((double)s1f + gumbel64(bb1), w1);
    if (w2i >= 0) {
      const unsigned bb2 = tfbits(ib + (unsigned)w2i);
      const float s2f = sb[w2i];
      const float sc2 = s2f + gumbel32(bb2);
      if ((sc1 - sc2) < 1e-4f) {
        const unsigned long long u2 =
            packcell((double)s2f + gumbel64(bb2), w2i);
        if (u2 > pb) pb = u2;
      }
    }
    atomicMax(&cells[cell], pb);
  }
}

// ---------- epilogue (fp32): 5 interleaved V-GEMVs per wave, softmax over K, context ----------
__global__ __launch_bounds__(256) void kfinal(
    const float* __restrict__ ge, const float* __restrict__ Wv,
    const float* __restrict__ bv, const float* __restrict__ Qm,
    const unsigned long long* __restrict__ cells, float* __restrict__ out) {
  const int b = blockIdx.x;
  const int t = threadIdx.x;
  const int wv = t >> 6;
  const int lane = t & 63;
  __shared__ float sc[20];
  __shared__ float ctxp[4][128];
  const float2 qv = ((const float2*)(Qm + b * 128))[lane];
  const float2 bvv = ((const float2*)bv)[lane];
  const float* gr[5];
  float2 V[5];
  #pragma unroll
  for (int j = 0; j < 5; ++j) {
    const unsigned long long cell = cells[b * 20 + wv * 5 + j];
    const int n = 32767 - (int)(cell & 0x7FFFull);
    gr[j] = ge + (size_t)n * 256;
    V[j] = bvv;
  }
  for (int f = 0; f < 256; f += 4) {
    const float2 w0 = ((const float2*)(Wv + (size_t)(f + 0) * 128))[lane];
    const float2 w1 = ((const float2*)(Wv + (size_t)(f + 1) * 128))[lane];
    const float2 w2_ = ((const float2*)(Wv + (size_t)(f + 2) * 128))[lane];
    const float2 w3 = ((const float2*)(Wv + (size_t)(f + 3) * 128))[lane];
    #pragma unroll
    for (int j = 0; j < 5; ++j) {
      const float4 gv = *(const float4*)(gr[j] + f);   // uniform -> s_load
      V[j].x = fmaf(gv.x, w0.x, V[j].x); V[j].y = fmaf(gv.x, w0.y, V[j].y);
      V[j].x = fmaf(gv.y, w1.x, V[j].x); V[j].y = fmaf(gv.y, w1.y, V[j].y);
      V[j].x = fmaf(gv.z, w2_.x, V[j].x); V[j].y = fmaf(gv.z, w2_.y, V[j].y);
      V[j].x = fmaf(gv.w, w3.x, V[j].x); V[j].y = fmaf(gv.w, w3.y, V[j].y);
    }
  }
  #pragma unroll
  for (int j = 0; j < 5; ++j) {
    float pr = qv.x * V[j].x + qv.y * V[j].y;
    #pragma unroll
    for (int off = 32; off; off >>= 1) pr += __shfl_xor(pr, off, 64);
    if (lane == 0) sc[wv * 5 + j] = pr * 0.08838834764831845f;  // 1/sqrt(128)
  }
  __syncthreads();
  float m = -3.0e38f;
  #pragma unroll
  for (int i = 0; i < 20; ++i) m = fmaxf(m, sc[i]);
  float s = 0.f;
  #pragma unroll
  for (int i = 0; i < 20; ++i) s += expf(sc[i] - m);
  const float inv = 1.0f / s;
  float c0 = 0.f, c1 = 0.f;
  #pragma unroll
  for (int j = 0; j < 5; ++j) {
    const float wk = expf(sc[wv * 5 + j] - m) * inv;
    c0 = fmaf(wk, V[j].x, c0);
    c1 = fmaf(wk, V[j].y, c1);
  }
  ctxp[wv][2 * lane] = c0;
  ctxp[wv][2 * lane + 1] = c1;
  __syncthreads();
  if (t < 128)
    out[b * 128 + t] = (ctxp[0][t] + ctxp[1][t]) + (ctxp[2][t] + ctxp[3][t]);
}

extern "C" void kernel_launch(void* const* d_in, const int* in_sizes, int n_in,
                              void* d_out, int out_size, void* d_ws, size_t ws_size,
                              hipStream_t stream) {
  (void)in_sizes; (void)n_in; (void)out_size; (void)ws_size;
  const float* pe = (const float*)d_in[0];
  const float* ge = (const float*)d_in[1];
  const float* Wq = (const float*)d_in[2];
  const float* bq = (const float*)d_in[3];
  const float* Wk = (const float*)d_in[4];
  const float* bk = (const float*)d_in[5];
  const float* Wv = (const float*)d_in[6];
  const float* bvp = (const float*)d_in[7];
  const float* W1 = (const float*)d_in[8];
  const float* b1 = (const float*)d_in[9];
  const float* w2 = (const float*)d_in[10];
  // d_in[11] = b2: uniform over n -> cancels in argmax; absent from output path.

  char* w = (char*)d_ws;
  float* Wf32 = (float*)w;                               // 131072 B
  double* qbT = (double*)(w + 131072);                   // 65536 B
  float* Qm = (float*)(w + 196608);                      // 32768 B
  unsigned long long* cells =
      (unsigned long long*)(w + 229376);                 // 10240 B
  double2* c12 = (double2*)(w + 239616);                 // 2048 B
  float* simg = (float*)(w + 262144);                    // 5,120,000 B (~5.4 MB total)
  float* out = (float*)d_out;

  kprep<<<dim3(321), dim3(128), 0, stream>>>(pe, Wq, bq, Wk, bk, W1, b1, w2,
                                             Wf32, qbT, Qm, cells, c12);
  ksim<<<dim3(1250), dim3(256), 0, stream>>>(ge, Wf32, qbT, c12, simg);
  kargmax<<<dim3(2560), dim3(256), 0, stream>>>(simg, cells);
  kfinal<<<dim3(64), dim3(256), 0, stream>>>(ge, Wv, bvp, Qm, cells, out);
}

// Round 5
// 259.719 us; speedup vs baseline: 1.2535x; 1.0497x over previous
//
#include <hip/hip_runtime.h>

#define NG 20000

// single-instruction rotate (v_alignbit_b32): rotl(x,r) == alignbit(x,x,32-r)
__device__ __forceinline__ unsigned rotl32(unsigned x, int r) {
  return __builtin_amdgcn_alignbit(x, x, 32 - r);
}

// ---------- JAX threefry2x32, key = (0, 42) ----------
__device__ __forceinline__ void threefry2x32(unsigned x0, unsigned x1,
                                             unsigned& o0, unsigned& o1) {
  const unsigned ks0 = 0u;
  const unsigned ks1 = 42u;
  const unsigned ks2 = 0x1BD11BDAu ^ 0u ^ 42u;
  x0 += ks0; x1 += ks1;
#define TFR(r) { x0 += x1; x1 = rotl32(x1, (r)); x1 ^= x0; }
  TFR(13) TFR(15) TFR(26) TFR(6)
  x0 += ks1; x1 += ks2 + 1u;
  TFR(17) TFR(29) TFR(16) TFR(24)
  x0 += ks2; x1 += ks0 + 2u;
  TFR(13) TFR(15) TFR(26) TFR(6)
  x0 += ks0; x1 += ks1 + 3u;
  TFR(17) TFR(29) TFR(16) TFR(24)
  x0 += ks1; x1 += ks2 + 4u;
  TFR(13) TFR(15) TFR(26) TFR(6)
  x0 += ks2; x1 += ks0 + 5u;
#undef TFR
  o0 = x0; o1 = x1;
}

// JAX threefry_partitionable: bits(i) = o0 ^ o1 of threefry((0,42),(0,i))
__device__ __forceinline__ unsigned tfbits(unsigned ctr) {
  unsigned o0, o1;
  threefry2x32(0u, ctr, o0, o1);
  return o0 ^ o1;
}

// fp32 fast-screen gumbel, constant-folded: g = -ln2*log2(-log2(u)) - ln(ln2)
__device__ __forceinline__ float gumbel32(unsigned bits) {
  float f = __uint_as_float((bits >> 9) | 0x3f800000u) - 1.0f;
  float u = fmaxf(f, 1.17549435e-38f);
  const float l2u = __log2f(u);                     // strictly < 0
  return fmaf(-0.69314718056f, __log2f(-l2u), 0.3665129206f);
}

// exact fp64 gumbel; u is a 23-bit dyadic rational, exact in double
__device__ __forceinline__ double gumbel64(unsigned bits) {
  float f = __uint_as_float((bits >> 9) | 0x3f800000u) - 1.0f;
  double u = (double)fmaxf(f, 1.17549435e-38f);
  return -log(-log(u));
}

// pack fp64 score (top 49 monotone bits) + 15-bit (32767-n): u64 max == (score, then smaller n)
__device__ __forceinline__ unsigned long long packcell(double v, int n) {
  unsigned long long u = (unsigned long long)__double_as_longlong(v);
  u = (u >> 63) ? ~u : (u | 0x8000000000000000ull);
  return (u & 0xFFFFFFFFFFFF8000ull) | (unsigned long long)(32767 - n);
}

// monotone fp32 pack (high 32) + gene index (low 32) for top-2 reduction
__device__ __forceinline__ unsigned long long packscreen(float v, int n) {
  unsigned u = __float_as_uint(v);
  u = (u >> 31) ? ~u : (u | 0x80000000u);
  return ((unsigned long long)u << 32) | (unsigned)n;
}

// ---------- prep: Wf=Wk@W1k (fp64 math, fp32 store), Q, qbT; c12; zero cells ----------
__global__ __launch_bounds__(128) void kprep(
    const float* __restrict__ pe, const float* __restrict__ Wq,
    const float* __restrict__ bq, const float* __restrict__ Wk,
    const float* __restrict__ bk, const float* __restrict__ W1,
    const float* __restrict__ b1, const float* __restrict__ w2,
    float* __restrict__ Wf32, double* __restrict__ qbT,
    float* __restrict__ Qm, unsigned long long* __restrict__ cells,
    double2* __restrict__ c12) {
  __shared__ float L[512];
  __shared__ double Ld[128];
  const int t = threadIdx.x;
  const int bid = blockIdx.x;
  if (bid < 256) {
    L[t] = Wk[bid * 128 + t];
    __syncthreads();
    double acc = 0.0;
    #pragma unroll 16
    for (int j = 0; j < 128; ++j)
      acc = fma((double)L[j], (double)W1[(128 + j) * 128 + t], acc);
    Wf32[bid * 128 + t] = (float)acc;
  } else if (bid < 320) {
    const int b = bid - 256;
    #pragma unroll
    for (int i = 0; i < 4; ++i) L[t + 128 * i] = pe[b * 512 + t + 128 * i];
    __syncthreads();
    double q = (double)bq[t];
    #pragma unroll 16
    for (int f = 0; f < 512; ++f)
      q = fma((double)L[f], (double)Wq[f * 128 + t], q);
    Qm[b * 128 + t] = (float)q;   // epilogue path stays fp32
    Ld[t] = q;
    __syncthreads();
    // qb[b,d=t] = Q@W1[:128] + b1 + bk@W1[128:]; store transposed qbT[d][b]
    double acc = (double)b1[t];
    #pragma unroll 8
    for (int j = 0; j < 128; ++j) {
      acc = fma(Ld[j], (double)W1[j * 128 + t], acc);
      acc = fma((double)bk[j], (double)W1[(128 + j) * 128 + t], acc);
    }
    qbT[t * 64 + b] = acc;
  } else {
    for (int i = t; i < 1280; i += 128) cells[i] = 0ull;
    const double w2d = (double)w2[t];
    c12[t] = make_double2(0.55 * w2d, 0.45 * w2d);
  }
}

// ---------- ksim: kp(fp32 GEMM) + sim(fp64) -> simg[64][20000] (NO atomics) ----------
// 1250 blocks x 256 thr, 16 genes/block. Phase 1 reworked vs R4: Wf32 is staged
// in cooperative 32-f LDS tiles (16 KB, 8 tiles, single-buffered) so the block
// reads each Wf32 element ONCE from L2 (128 KB/block -> 160 MB total vs 640 MB
// when every wave streamed the full matrix; VMEM insts/thread 512 -> 32).
// Thread mapping unchanged: wave wv owns genes wv*4..wv*4+3, thread owns
// d = {2*lane, 2*lane+1}; per-acc fma order f-ascending with identical W values
// -> kp bit-identical to R4. LDS: 16 KB geL/simLf + 16 KB Wt + 8 KB kpL = 40 KB
// -> 4 blocks/CU, matching the 4.88 blocks/CU grid supply.
// Wt reads: bank = 2*lane mod 32 -> 2-way conflict = free (m136). Gene reads:
// wave-uniform addr -> LDS broadcast.
// Phase 2: fp64 sim, wave wv computes genes {wv,wv+4,wv+8,wv+12}, lane = batch;
// identical fp64 op order. Then transpose simLf via LDS, coalesced float4 store.
__global__ __launch_bounds__(256) void ksim(
    const float* __restrict__ ge, const float* __restrict__ Wf32,
    const double* __restrict__ qbT, const double2* __restrict__ c12,
    float* __restrict__ simg) {
  __shared__ double SBd[2048];   // 16 KB: phase1 geL; phase2 simLf [64][17]
  __shared__ float Wt[4096];     // 16 KB: one 32-f x 128-d W tile
  __shared__ float kpL[2048];    // 8 KB: kp[16][128]
  float* geL = (float*)SBd;
  float* simLf = (float*)SBd;
  const int t = threadIdx.x;
  const int wv = t >> 6;
  const int lane = t & 63;
  const int g0 = blockIdx.x * 16;     // 1250 blocks * 16 genes

  // stage ge tile (16 genes x 256 f) -> LDS: 4 independent float4 per thread
  // (ordered before first compute by the first in-loop barrier)
  {
    const float4* src = (const float4*)(ge + (size_t)g0 * 256);
    float4* dst = (float4*)geL;
    #pragma unroll
    for (int i = 0; i < 4; ++i) dst[t + i * 256] = src[t + i * 256];
  }

  // ---- phase 1: fp32 GEMM, W in single-buffered 32-f LDS tiles ----
  float acc[4][2];
  #pragma unroll
  for (int j = 0; j < 4; ++j) { acc[j][0] = 0.f; acc[j][1] = 0.f; }
  const float* gL = geL + wv * 4 * 256;

  for (int tile = 0; tile < 8; ++tile) {
    __syncthreads();   // tile 0: geL staged; else: prev tile's Wt reads done
    {
      const float4* wsrc = (const float4*)(Wf32 + tile * 32 * 128);
      float4* wdst = (float4*)Wt;
      #pragma unroll
      for (int i = 0; i < 4; ++i) wdst[t + i * 256] = wsrc[t + i * 256];
    }
    __syncthreads();
    #pragma unroll
    for (int fr = 0; fr < 32; fr += 4) {
      const int f0 = tile * 32 + fr;
      const float2 w0 = *(const float2*)(Wt + (fr + 0) * 128 + 2 * lane);
      const float2 w1 = *(const float2*)(Wt + (fr + 1) * 128 + 2 * lane);
      const float2 w2 = *(const float2*)(Wt + (fr + 2) * 128 + 2 * lane);
      const float2 w3 = *(const float2*)(Wt + (fr + 3) * 128 + 2 * lane);
      #pragma unroll
      for (int j = 0; j < 4; ++j) {
        const float4 gv = *(const float4*)(gL + j * 256 + f0);  // LDS broadcast
        acc[j][0] = fmaf(gv.x, w0.x, acc[j][0]);
        acc[j][1] = fmaf(gv.x, w0.y, acc[j][1]);
        acc[j][0] = fmaf(gv.y, w1.x, acc[j][0]);
        acc[j][1] = fmaf(gv.y, w1.y, acc[j][1]);
        acc[j][0] = fmaf(gv.z, w2.x, acc[j][0]);
        acc[j][1] = fmaf(gv.z, w2.y, acc[j][1]);
        acc[j][0] = fmaf(gv.w, w3.x, acc[j][0]);
        acc[j][1] = fmaf(gv.w, w3.y, acc[j][1]);
      }
    }
  }

  __syncthreads();   // geL reads done (SBd about to be reused as simLf)
  #pragma unroll
  for (int j = 0; j < 4; ++j)
    ((float2*)(kpL + (wv * 4 + j) * 128))[lane] =
        make_float2(acc[j][0], acc[j][1]);
  __syncthreads();

  // ---- phase 2: fp64 sim (4 genes/wave, lane = batch) ----
  double s[4];
  #pragma unroll
  for (int j = 0; j < 4; ++j) s[j] = 0.0;
  for (int dd = 0; dd < 128; ++dd) {
    const double2 cc = c12[dd];                   // uniform -> s_load
    const double qv = qbT[dd * 64 + lane];        // coalesced, L1-hot
    #pragma unroll
    for (int j = 0; j < 4; ++j) {
      const double kv = (double)kpL[(wv + j * 4) * 128 + dd];  // broadcast
      const double tt = qv + kv;
      s[j] = fma(tt, cc.x, s[j]);
      s[j] = fma(fabs(tt), cc.y, s[j]);
    }
  }
  #pragma unroll
  for (int j = 0; j < 4; ++j)
    simLf[lane * 17 + (wv + j * 4)] = (float)(2.0 * s[j]);
  __syncthreads();

  // ---- transpose-store: thread t -> b = t>>2, gene-chunk = t&3 (float4) ----
  {
    const int b = t >> 2;
    const int gc = t & 3;
    float4 v;
    v.x = simLf[b * 17 + gc * 4 + 0];
    v.y = simLf[b * 17 + gc * 4 + 1];
    v.z = simLf[b * 17 + gc * 4 + 2];
    v.w = simLf[b * 17 + gc * 4 + 3];
    *(float4*)(simg + (size_t)b * NG + g0 + gc * 4) = v;
  }
}

// ---------- kargmax: 2 windows per cell, pairwise-ILP screen, atomicMax merge ----------
// 2560 blocks x 256 thr. Block = (cell, window); window = 10000 genes.
// Inner loop processes gene pairs (n, n+256): two independent threefry chains
// interleave in the issue slots. fp32 top-2 per thread; packed-u64 top-2 wave
// butterfly; cross-wave LDS merge; thread 0 fp64-exact window winner
// (+ runner-up iff fp32 gap < 1e-4, screen err 2e-5 << margin) -> ONE atomicMax
// per window (2 writers/cell: contention-free; cells zeroed by kprep).
// Max of exact window winners == exact global argmax (window-size-independent).
// R4 counters: VALUBusy 92%, issue-bound on the ~85-inst/eval stream (70 =
// exact threefry, irreducible) -> left unchanged this round.
__global__ __launch_bounds__(256) void kargmax(
    const float* __restrict__ simg, unsigned long long* __restrict__ cells) {
  __shared__ unsigned long long R1s[4], R2s[4];
  const int cell = blockIdx.x >> 1;            // = b*20 + k
  const int wdw = blockIdx.x & 1;
  const int t = threadIdx.x;
  const int wv = t >> 6;
  const int lane = t & 63;
  const int b = (unsigned)cell / 20u;
  const float* sb = simg + (size_t)b * NG;
  const unsigned ib = (unsigned)cell * (unsigned)NG;
  const int base = wdw * 10000;
  const int end = base + 10000;

  float m1 = -3e38f, m2 = -3e38f;
  int n1 = -1, n2 = -1;
  int n = base + t;
  // pair loop: candidates n and n+256 (independent threefry chains -> ILP 2)
  for (; n + 256 < end; n += 512) {
    const unsigned bbA = tfbits(ib + (unsigned)n);
    const unsigned bbB = tfbits(ib + (unsigned)(n + 256));
    const float sA = sb[n] + gumbel32(bbA);
    const float sB = sb[n + 256] + gumbel32(bbB);
    if (sA > m1) { m2 = m1; n2 = n1; m1 = sA; n1 = n; }
    else if (sA > m2) { m2 = sA; n2 = n; }
    if (sB > m1) { m2 = m1; n2 = n1; m1 = sB; n1 = n + 256; }
    else if (sB > m2) { m2 = sB; n2 = n + 256; }
  }
  for (; n < end; n += 256) {
    const unsigned bb = tfbits(ib + (unsigned)n);
    const float sc = sb[n] + gumbel32(bb);
    if (sc > m1) { m2 = m1; n2 = n1; m1 = sc; n1 = n; }
    else if (sc > m2) { m2 = sc; n2 = n; }
  }
  unsigned long long p1 = packscreen(m1, n1);
  unsigned long long p2 = packscreen(m2, n2);
  // wave top-2 butterfly: merge sorted pairs (p1>=p2), (q1>=q2)
  #pragma unroll
  for (int off = 32; off; off >>= 1) {
    unsigned long long q1 = __shfl_xor(p1, off, 64);
    unsigned long long q2 = __shfl_xor(p2, off, 64);
    if (q1 > p1) {
      unsigned long long t1 = p1;
      p1 = q1;
      p2 = (q2 > t1) ? q2 : t1;
    } else {
      p2 = (q1 > p2) ? q1 : p2;
    }
  }
  if (lane == 0) { R1s[wv] = p1; R2s[wv] = p2; }
  __syncthreads();
  if (t == 0) {
    unsigned long long P1 = R1s[0], P2 = R2s[0];
    #pragma unroll
    for (int w = 1; w < 4; ++w) {
      unsigned long long q1 = R1s[w], q2 = R2s[w];
      if (q1 > P1) {
        unsigned long long t1 = P1;
        P1 = q1;
        P2 = (q2 > t1) ? q2 : t1;
      } else {
        P2 = (q1 > P2) ? q1 : P2;
      }
    }
    const int w1 = (int)(P1 & 0xFFFFFFFFull);
    const int w2i = (int)(P2 & 0xFFFFFFFFull);
    const unsigned bb1 = tfbits(ib + (unsigned)w1);
    const float s1f = sb[w1];
    const float sc1 = s1f + gumbel32(bb1);
    unsigned long long pb = packcell((double)s1f + gumbel64(bb1), w1);
    if (w2i >= 0) {
      const unsigned bb2 = tfbits(ib + (unsigned)w2i);
      const float s2f = sb[w2i];
      const float sc2 = s2f + gumbel32(bb2);
      if ((sc1 - sc2) < 1e-4f) {
        const unsigned long long u2 =
            packcell((double)s2f + gumbel64(bb2), w2i);
        if (u2 > pb) pb = u2;
      }
    }
    atomicMax(&cells[cell], pb);
  }
}

// ---------- epilogue (fp32): 5 interleaved V-GEMVs per wave, softmax over K, context ----------
__global__ __launch_bounds__(256) void kfinal(
    const float* __restrict__ ge, const float* __restrict__ Wv,
    const float* __restrict__ bv, const float* __restrict__ Qm,
    const unsigned long long* __restrict__ cells, float* __restrict__ out) {
  const int b = blockIdx.x;
  const int t = threadIdx.x;
  const int wv = t >> 6;
  const int lane = t & 63;
  __shared__ float sc[20];
  __shared__ float ctxp[4][128];
  const float2 qv = ((const float2*)(Qm + b * 128))[lane];
  const float2 bvv = ((const float2*)bv)[lane];
  const float* gr[5];
  float2 V[5];
  #pragma unroll
  for (int j = 0; j < 5; ++j) {
    const unsigned long long cell = cells[b * 20 + wv * 5 + j];
    const int n = 32767 - (int)(cell & 0x7FFFull);
    gr[j] = ge + (size_t)n * 256;
    V[j] = bvv;
  }
  for (int f = 0; f < 256; f += 4) {
    const float2 w0 = ((const float2*)(Wv + (size_t)(f + 0) * 128))[lane];
    const float2 w1 = ((const float2*)(Wv + (size_t)(f + 1) * 128))[lane];
    const float2 w2_ = ((const float2*)(Wv + (size_t)(f + 2) * 128))[lane];
    const float2 w3 = ((const float2*)(Wv + (size_t)(f + 3) * 128))[lane];
    #pragma unroll
    for (int j = 0; j < 5; ++j) {
      const float4 gv = *(const float4*)(gr[j] + f);   // uniform -> s_load
      V[j].x = fmaf(gv.x, w0.x, V[j].x); V[j].y = fmaf(gv.x, w0.y, V[j].y);
      V[j].x = fmaf(gv.y, w1.x, V[j].x); V[j].y = fmaf(gv.y, w1.y, V[j].y);
      V[j].x = fmaf(gv.z, w2_.x, V[j].x); V[j].y = fmaf(gv.z, w2_.y, V[j].y);
      V[j].x = fmaf(gv.w, w3.x, V[j].x); V[j].y = fmaf(gv.w, w3.y, V[j].y);
    }
  }
  #pragma unroll
  for (int j = 0; j < 5; ++j) {
    float pr = qv.x * V[j].x + qv.y * V[j].y;
    #pragma unroll
    for (int off = 32; off; off >>= 1) pr += __shfl_xor(pr, off, 64);
    if (lane == 0) sc[wv * 5 + j] = pr * 0.08838834764831845f;  // 1/sqrt(128)
  }
  __syncthreads();
  float m = -3.0e38f;
  #pragma unroll
  for (int i = 0; i < 20; ++i) m = fmaxf(m, sc[i]);
  float s = 0.f;
  #pragma unroll
  for (int i = 0; i < 20; ++i) s += expf(sc[i] - m);
  const float inv = 1.0f / s;
  float c0 = 0.f, c1 = 0.f;
  #pragma unroll
  for (int j = 0; j < 5; ++j) {
    const float wk = expf(sc[wv * 5 + j] - m) * inv;
    c0 = fmaf(wk, V[j].x, c0);
    c1 = fmaf(wk, V[j].y, c1);
  }
  ctxp[wv][2 * lane] = c0;
  ctxp[wv][2 * lane + 1] = c1;
  __syncthreads();
  if (t < 128)
    out[b * 128 + t] = (ctxp[0][t] + ctxp[1][t]) + (ctxp[2][t] + ctxp[3][t]);
}

extern "C" void kernel_launch(void* const* d_in, const int* in_sizes, int n_in,
                              void* d_out, int out_size, void* d_ws, size_t ws_size,
                              hipStream_t stream) {
  (void)in_sizes; (void)n_in; (void)out_size; (void)ws_size;
  const float* pe = (const float*)d_in[0];
  const float* ge = (const float*)d_in[1];
  const float* Wq = (const float*)d_in[2];
  const float* bq = (const float*)d_in[3];
  const float* Wk = (const float*)d_in[4];
  const float* bk = (const float*)d_in[5];
  const float* Wv = (const float*)d_in[6];
  const float* bvp = (const float*)d_in[7];
  const float* W1 = (const float*)d_in[8];
  const float* b1 = (const float*)d_in[9];
  const float* w2 = (const float*)d_in[10];
  // d_in[11] = b2: uniform over n -> cancels in argmax; absent from output path.

  char* w = (char*)d_ws;
  float* Wf32 = (float*)w;                               // 131072 B
  double* qbT = (double*)(w + 131072);                   // 65536 B
  float* Qm = (float*)(w + 196608);                      // 32768 B
  unsigned long long* cells =
      (unsigned long long*)(w + 229376);                 // 10240 B
  double2* c12 = (double2*)(w + 239616);                 // 2048 B
  float* simg = (float*)(w + 262144);                    // 5,120,000 B (~5.4 MB total)
  float* out = (float*)d_out;

  kprep<<<dim3(321), dim3(128), 0, stream>>>(pe, Wq, bq, Wk, bk, W1, b1, w2,
                                             Wf32, qbT, Qm, cells, c12);
  ksim<<<dim3(1250), dim3(256), 0, stream>>>(ge, Wf32, qbT, c12, simg);
  kargmax<<<dim3(2560), dim3(256), 0, stream>>>(simg, cells);
  kfinal<<<dim3(64), dim3(256), 0, stream>>>(ge, Wv, bvp, Qm, cells, out);
}